// Round 2
// baseline (106.071 us; speedup 1.0000x reference)
//
#include <hip/hip_runtime.h>
#include <hip/hip_bf16.h>
#include <math.h>

// Contrastive (NT-Xent-like) loss over x[16384][64] fp32.
//   x_hat = sqrt(2*log2e) * x / ||x||   (so exp(sim/T) = exp2(x_hat_i.x_hat_j))
//   den[j] = sum_i exp2(x_hat_i . x_hat_j) - e^2
//   num[j] = exp2(x_hat_{j^1} . x_hat_j)
//   out = -log( mean_j num[j] / den[j] )
//
// Round 16: r15 never ran (GPU broker timeout) — resubmitting byte-identical.
// r15 rationale: r14 (occupancy 3->4 waves/SIMD) bought only -1.4 us => den is
// NOT TLP-starved; the per-block serial structure is the stall (stage 32 KB ->
// syncthreads vmcnt(0) drain -> compute, paid cold by all 8256 blocks).
// PERSISTENT den: 512 blocks (2/CU, 66 KB LDS), each walks a contiguous chunk
// of ~16 tile-pairs with double-buffered A/B staging: issue next pair's 8
// global_load_lds -> counted s_waitcnt vmcnt(8) (never 0) -> raw s_barrier +
// sched_barrier(0) -> compute cur pair (math byte-identical to r13/r14) ->
// single __syncthreads at the combine (its implicit vmcnt(0) drain lands
// ~2500 cyc after DMA issue => free). red[] gets dedicated 2 KB (no longer
// aliases a live buffer). Contiguous bt per block => same-ti runs => A-tile
// L2 hits; xnb (2 MB) is L2-resident per XCD anyway.
// Success signature: total 84-89 us, den VALUBusy >=75%.
// Failure signatures: total ~99 (overlap wasn't the stall) or >105 / wrong
// result (dbuf race) -> revert to r14.

#define NROWS 16384
#define KDIM 64
#define NTILE 128
#define NTB (NROWS / NTILE)          // 128 tile-blocks per side
#define NPAIRS (NTB * (NTB + 1) / 2) // 8256 upper-triangle tile pairs
#define DEN_BLOCKS 512               // 2 per CU (LDS-bound)

typedef __attribute__((ext_vector_type(8))) short short8;   // 8 bf16 = 4 VGPRs
typedef __attribute__((ext_vector_type(4))) float f32x4;
typedef __attribute__((ext_vector_type(2))) float f32x2;

__device__ __forceinline__ float exp2_fast(float x) {
#if __has_builtin(__builtin_amdgcn_exp2f)
    return __builtin_amdgcn_exp2f(x);   // bare v_exp_f32
#else
    return exp2f(x);
#endif
}

// async global->LDS DMA, 16 B per lane; LDS side must be uniform + lane*16.
__device__ __forceinline__ void load_lds16(const void* g, void* l) {
    __builtin_amdgcn_global_load_lds((const __attribute__((address_space(1))) unsigned int*)g,
                                     (__attribute__((address_space(3))) unsigned int*)l,
                                     16, 0, 0);
}

// ---- kernel A: row-normalize, prescale by sqrt(2*log2e) -> bf16 -----------
// 64 rows/block, 4 lanes/row, 16 floats/thread. Also zeroes ctrl/accum.
__global__ __launch_bounds__(256) void normalize_kernel(const float* __restrict__ x,
                                                        unsigned short* __restrict__ xnb,
                                                        unsigned int* __restrict__ ctrl,
                                                        float* __restrict__ accum) {
    const int t = threadIdx.x;
    const int r = blockIdx.x * 64 + (t >> 2);
    const int q = t & 3;
    const float4* xr = (const float4*)(x + (size_t)r * KDIM) + q * 4;
    const float4 v0 = xr[0], v1 = xr[1], v2 = xr[2], v3 = xr[3];
    float ss = v0.x * v0.x + v0.y * v0.y + v0.z * v0.z + v0.w * v0.w
             + v1.x * v1.x + v1.y * v1.y + v1.z * v1.z + v1.w * v1.w
             + v2.x * v2.x + v2.y * v2.y + v2.z * v2.z + v2.w * v2.w
             + v3.x * v3.x + v3.y * v3.y + v3.z * v3.z + v3.w * v3.w;
    ss += __shfl_xor(ss, 1, 64);
    ss += __shfl_xor(ss, 2, 64);
    // sqrt(2*log2(e)) = sqrt(2.88539008) = 1.69864404
    const float a = 1.69864404f * rsqrtf(fmaxf(ss, 1e-16f));
    const float vals[16] = {v0.x * a, v0.y * a, v0.z * a, v0.w * a,
                            v1.x * a, v1.y * a, v1.z * a, v1.w * a,
                            v2.x * a, v2.y * a, v2.z * a, v2.w * a,
                            v3.x * a, v3.y * a, v3.z * a, v3.w * a};
    union { unsigned short us[16]; uint4 v[2]; } o;
    #pragma unroll
    for (int k = 0; k < 16; k++) {
        __hip_bfloat16 b = __float2bfloat16(vals[k]);
        o.us[k] = *(unsigned short*)&b;
    }
    uint4* dst = (uint4*)(xnb + (size_t)r * KDIM);
    dst[q * 2] = o.v[0];
    dst[q * 2 + 1] = o.v[1];
    if (blockIdx.x == 0 && t == 0) { ctrl[0] = 0u; ctrl[1] = 0u; accum[0] = 0.0f; }
}

// ---- kernel B: persistent, double-buffered symmetric tile-pair sums -------
// Block = contiguous chunk of ~16 upper-triangle tile pairs. 4 waves 2x2,
// 64x64/wave, mfma_f32_16x16x32_bf16. Both tiles staged via global_load_lds
// width=16, XOR-swizzled chunk(r,q) at r*8 + (q^(r&7)): coalesced staging,
// 0 bank conflicts (verified r3-r13). Double-buffered: next pair's DMA in
// flight under current pair's compute; counted vmcnt(8), raw s_barrier.
// LDS 66 KB -> 2 blocks/CU (occupancy drop is intended; r14 showed den is
// not TLP-limited).
__global__ __launch_bounds__(256, 2) void den_kernel(const unsigned short* __restrict__ xnb,
                                                     float* __restrict__ S,
                                                     float* __restrict__ num) {
    __shared__ float4 Abuf[2][1024];  // 2 x 16 KB
    __shared__ float4 Bbuf[2][1024];  // 2 x 16 KB
    __shared__ float red[512];        // 2 KB cross-wave combine scratch

    const int t = threadIdx.x;
    const int b = blockIdx.x;
    int bt = (b * NPAIRS) / DEN_BLOCKS;                 // contiguous chunk
    const int btEnd = ((b + 1) * NPAIRS) / DEN_BLOCKS;  // 16 or 17 pairs

    // triangular decode of the chunk start (f32; loops absorb rounding)
    int ti = (int)((257.0f - sqrtf(66049.0f - 8.0f * (float)bt)) * 0.5f);
    while (ti * NTB - ti * (ti - 1) / 2 > bt) ti--;
    while ((ti + 1) * NTB - (ti + 1) * ti / 2 <= bt) ti++;
    int tj = ti + (bt - (ti * NTB - ti * (ti - 1) / 2));

    // per-thread staging pattern: chunk c -> row r=c>>3, k-chunk q=(c&7)^(r&7).
    // Global side is a per-lane VGPR address (swizzle allowed); LDS side is
    // uniform + lane*16.
    int rr[4], qq[4];
    #pragma unroll
    for (int s = 0; s < 4; s++) {
        const int c = s * 256 + t;
        rr[s] = c >> 3;
        qq[s] = ((c & 7) ^ (rr[s] & 7)) * 8;
    }

    // prologue: stage first pair into buffer 0
    #pragma unroll
    for (int s = 0; s < 4; s++) {
        const int c = s * 256 + t;
        load_lds16(xnb + (size_t)(ti * NTILE + rr[s]) * KDIM + qq[s], &Abuf[0][c]);
        load_lds16(xnb + (size_t)(tj * NTILE + rr[s]) * KDIM + qq[s], &Bbuf[0][c]);
    }

    const int lane = t & 63, w = t >> 6;
    const int wi = w >> 1, wj = w & 1;
    const int m = lane & 15, p = lane >> 4;

    int cur = 0;
    int nti = ti, ntj = tj;

    for (; bt < btEnd; ++bt) {
        // issue NEXT pair's staging into buf[cur^1], then counted wait:
        // vmcnt(8) retires cur's DMAs (FIFO) while next's 8 stay in flight.
        if (bt + 1 < btEnd) {
            ntj++; if (ntj == NTB) { nti++; ntj = nti; }
            #pragma unroll
            for (int s = 0; s < 4; s++) {
                const int c = s * 256 + t;
                load_lds16(xnb + (size_t)(nti * NTILE + rr[s]) * KDIM + qq[s], &Abuf[cur ^ 1][c]);
                load_lds16(xnb + (size_t)(ntj * NTILE + rr[s]) * KDIM + qq[s], &Bbuf[cur ^ 1][c]);
            }
            asm volatile("s_waitcnt vmcnt(8)" ::: "memory");
        } else {
            asm volatile("s_waitcnt vmcnt(0)" ::: "memory");
        }
        __builtin_amdgcn_sched_barrier(0);
        __builtin_amdgcn_s_barrier();       // raw: no compiler vmcnt(0) drain
        __builtin_amdgcn_sched_barrier(0);  // rule #18: pin ds_reads below

        const unsigned short* As = (const unsigned short*)Abuf[cur];
        const unsigned short* Bs = (const unsigned short*)Bbuf[cur];
        const bool diag = (ti == tj);
        const int ib = ti * NTILE, jb = tj * NTILE;

        const f32x4 zero = {0.f, 0.f, 0.f, 0.f};
        f32x4 acc[4][4];
        #pragma unroll
        for (int it = 0; it < 4; it++)
            #pragma unroll
            for (int jt = 0; jt < 4; jt++) acc[it][jt] = zero;

        #pragma unroll
        for (int kc = 0; kc < 2; kc++) {
            short8 af[4], bf[4];
            const int qx = ((kc << 2) | p) ^ (m & 7);
            #pragma unroll
            for (int it = 0; it < 4; it++) {
                af[it] = *(const short8*)(As + ((wi * 64 + it * 16 + m) * 8 + qx) * 8);
                bf[it] = *(const short8*)(Bs + ((wj * 64 + it * 16 + m) * 8 + qx) * 8);
            }
            #pragma unroll
            for (int it = 0; it < 4; it++)
                #pragma unroll
                for (int jt = 0; jt < 4; jt++)
                    acc[it][jt] = __builtin_amdgcn_mfma_f32_16x16x32_bf16(af[it], bf[jt], acc[it][jt], 0, 0, 0);
        }

        // epilogue: exp2; packed (v_pk_add_f32) accumulation of col/row partials
        f32x2 cs01 = {0.f, 0.f}, cs23 = {0.f, 0.f};
        float rs[16];
        #pragma unroll
        for (int it = 0; it < 4; it++) {
            #pragma unroll
            for (int reg = 0; reg < 4; reg++) {
                f32x2 e01, e23;
                e01.x = exp2_fast(acc[it][0][reg]);
                e01.y = exp2_fast(acc[it][1][reg]);
                e23.x = exp2_fast(acc[it][2][reg]);
                e23.y = exp2_fast(acc[it][3][reg]);
                cs01 += e01;
                cs23 += e23;
                const f32x2 rp = e01 + e23;
                rs[it * 4 + reg] = rp.x + rp.y;
            }
        }
        float cs[4] = {cs01.x, cs01.y, cs23.x, cs23.y};

        // colsum butterfly over p (value-halving): lane ends with column p*16+m
        {
            const bool hb = (p & 2) != 0;
            float s0 = hb ? cs[0] : cs[2], k0 = hb ? cs[2] : cs[0];
            float s1 = hb ? cs[1] : cs[3], k1 = hb ? cs[3] : cs[1];
            cs[0] = k0 + __shfl_xor(s0, 32, 64);
            cs[1] = k1 + __shfl_xor(s1, 32, 64);
            const bool lb = (p & 1) != 0;
            float s2 = lb ? cs[0] : cs[1], k2 = lb ? cs[1] : cs[0];
            cs[0] = k2 + __shfl_xor(s2, 16, 64);
        }

        // rowsum butterfly over m (value-halving, 15 shfl): lane ends with row
        // (m>>2)*16 + p*4 + (m&3)
        if (!diag) {
            #pragma unroll
            for (int k = 0; k < 8; k++) {
                const float snd = (m & 8) ? rs[k] : rs[k + 8];
                const float kp  = (m & 8) ? rs[k + 8] : rs[k];
                rs[k] = kp + __shfl_xor(snd, 8, 64);
            }
            #pragma unroll
            for (int k = 0; k < 4; k++) {
                const float snd = (m & 4) ? rs[k] : rs[k + 4];
                const float kp  = (m & 4) ? rs[k + 4] : rs[k];
                rs[k] = kp + __shfl_xor(snd, 4, 64);
            }
            #pragma unroll
            for (int k = 0; k < 2; k++) {
                const float snd = (m & 2) ? rs[k] : rs[k + 2];
                const float kp  = (m & 2) ? rs[k + 2] : rs[k];
                rs[k] = kp + __shfl_xor(snd, 2, 64);
            }
            {
                const float snd = (m & 1) ? rs[0] : rs[1];
                const float kp  = (m & 1) ? rs[1] : rs[0];
                rs[0] = kp + __shfl_xor(snd, 1, 64);
            }
        } else if (wi == wj) {
            // num[j] = exp2(acc(row j^1, col j)) from the diagonal tile: element
            // (m^1, m) of sub-tile it lives in lane ((m^1)>>2, m), reg (m^1)&3.
            const int pc = m ^ 1;
            if ((pc >> 2) == p) {
                #pragma unroll
                for (int it = 0; it < 4; it++)
                    num[jb + wj * 64 + it * 16 + m] = exp2_fast(acc[it][it][pc & 3]);
            }
        }

        // cross-wave combine through dedicated red[] (no aliasing of live bufs).
        // Writes need no leading barrier: any wave reaching here has passed this
        // iteration's s_barrier, and red readers of the PREVIOUS iteration were
        // joined by that same barrier.
        red[wi * 128 + wj * 64 + p * 16 + m] = cs[0];
        if (!diag) red[256 + wj * 128 + wi * 64 + ((m >> 2) * 16 + p * 4 + (m & 3))] = rs[0];
        __syncthreads();   // implicit vmcnt(0) drain: next-pair DMAs issued
                           // ~2500 cyc ago -> effectively free. Also fences all
                           // waves' As/Bs reads before buf[cur] is re-staged.

        // exactly-once coalesced partial stores (no atomics, no fences):
        //   colsums -> S[tj][ti][c] (den[jb+c]); rowsums -> S[ti][tj][r] (den[ib+r])
        if (t < NTILE) {
            S[((size_t)tj * NTB + ti) * NTILE + t] = red[t] + red[128 + t];
        } else if (!diag) {
            const int u = t - NTILE;
            S[((size_t)ti * NTB + tj) * NTILE + u] = red[256 + u] + red[256 + 128 + u];
        }

        ti = nti; tj = ntj; cur ^= 1;
    }
}

// ---- kernel C: den[a*128+c] = sum_b S[a][b][c]; ratio + global sum + log ---
// 128 blocks; ticket write of the final scalar (r6-verified).
__global__ __launch_bounds__(256) void reduce_kernel(const float* __restrict__ S,
                                                     const float* __restrict__ num,
                                                     unsigned int* __restrict__ ctrl,
                                                     float* __restrict__ accum,
                                                     float* __restrict__ out) {
    const int a = blockIdx.x;
    const int t = threadIdx.x;
    const int c = t & 127, h = t >> 7;     // h splits the b-range in two
    const float* base = S + (size_t)a * (NTB * NTILE) + (size_t)h * 64 * NTILE + c;
    float s = 0.0f;
    #pragma unroll 8
    for (int b = 0; b < 64; b++) s += base[(size_t)b * NTILE];

    __shared__ float part[NTILE];
    __shared__ float wsum[4];
    if (h == 0) part[c] = s;
    __syncthreads();

    float r = 0.0f;
    if (h == 1) {
        const float E2 = 7.38905609893065f;  // exp(1/T)=exp(2): diagonal removal
        r = num[a * NTILE + c] / ((part[c] + s) - E2);
    }
    #pragma unroll
    for (int o = 32; o > 0; o >>= 1) r += __shfl_xor(r, o, 64);
    if ((t & 63) == 0) wsum[t >> 6] = r;
    __syncthreads();
    if (t == 0) {
        const float bsum = (wsum[0] + wsum[1]) + (wsum[2] + wsum[3]);
        __hip_atomic_fetch_add(accum, bsum, __ATOMIC_RELAXED, __HIP_MEMORY_SCOPE_AGENT);
        const unsigned int tk = __hip_atomic_fetch_add(&ctrl[1], 1u, __ATOMIC_ACQ_REL, __HIP_MEMORY_SCOPE_AGENT);
        if (tk == (unsigned)(NTB - 1)) {   // last block writes the loss
            const float total = __hip_atomic_load(accum, __ATOMIC_ACQUIRE, __HIP_MEMORY_SCOPE_AGENT);
            out[0] = -logf(total / (float)NROWS);
        }
    }
}

extern "C" void kernel_launch(void* const* d_in, const int* in_sizes, int n_in,
                              void* d_out, int out_size, void* d_ws, size_t ws_size,
                              hipStream_t stream) {
    const float* x = (const float*)d_in[0];
    float* out = (float*)d_out;

    // ws: xnb [2 MB bf16] | num [64 KB f32] | accum [1 f32] | ctrl [2 u32] | S [8 MB f32]
    unsigned short* xnb = (unsigned short*)d_ws;
    float* num = (float*)((char*)d_ws + (size_t)NROWS * KDIM * sizeof(unsigned short));
    float* accum = num + NROWS;
    unsigned int* ctrl = (unsigned int*)(accum + 1);
    float* S = (float*)(ctrl + 2);

    normalize_kernel<<<NROWS / 64, 256, 0, stream>>>(x, xnb, ctrl, accum);
    den_kernel<<<DEN_BLOCKS, 256, 0, stream>>>(xnb, S, num);
    reduce_kernel<<<NTB, 256, 0, stream>>>(S, num, ctrl, accum, out);
}